// Round 2
// baseline (341.257 us; speedup 1.0000x reference)
//
#include <hip/hip_runtime.h>
#include <hip/hip_bf16.h>
#include <hip/hip_cooperative_groups.h>

namespace cg = cooperative_groups;

#define N_NODES 25000
#define KFAN    32
#define FIN     256
#define FOUT    256
#define NBLK    512            // 2 blocks/CU, all co-resident (cooperative)
#define NTILES  391            // gemm row-tiles of 64
#define GTILES  782            // 391 row-tiles x 2 col-halves
#define PUNITS  3128           // 782 node-blocks x 4 col-chunks

typedef float  f32x4  __attribute__((ext_vector_type(4)));
typedef short  s16x8  __attribute__((ext_vector_type(8)));

// round-to-nearest-even fp32 -> bf16 bits (scalar path)
__device__ __forceinline__ ushort f2bf(float f) {
    unsigned int u = __float_as_uint(f);
    u += 0x7fffu + ((u >> 16) & 1u);
    return (ushort)(u >> 16);
}

// packed RNE conversion: lo = bf16(a), hi = bf16(b) in one instruction
__device__ __forceinline__ unsigned int pack2(float a, float b) {
    unsigned int r;
    asm("v_cvt_pk_bf16_f32 %0, %1, %2" : "=v"(r) : "v"(a), "v"(b));
    return r;
}

// One fused cooperative kernel:
//   phase 0: Wt[n][k] = bf16(W[k][n])            (blocks 0..63)
//   phase 1: y = relu(x @ W + b)  via MFMA bf16  (tiles b, b+512)
//   phase 2: out[n][o] = max_k y[neigh[n][k]][o] (units b + 512j)
// grid.sync() between phases; __threadfence() (agent scope -> buffer_wbl2 on
// gfx950) for cross-XCD y/Wt visibility.
__global__ __launch_bounds__(256, 2) void fused(
    const float*  __restrict__ x,      // [N][FIN] fp32
    const int*    __restrict__ neigh,  // [N][KFAN]
    const float*  __restrict__ W,      // [FIN][FOUT] fp32
    const float*  __restrict__ bias,   // [FOUT]
    float*        __restrict__ out,    // [N][FOUT] fp32
    ushort*       __restrict__ y,      // [N][FOUT] bf16 bits (ws)
    ushort*       __restrict__ Wt)     // [FOUT][FIN] bf16 bits (ws+32MB)
{
    __shared__ union {
        float  ls[32][33];       // phase 0: 4.2 KB
        ushort As[64][264];      // phase 1: 33.8 KB (row 528B = 132dw ≡ 4 mod 32)
        int    nidx[32][36];     // phase 2: 4.6 KB
    } sm;

    cg::grid_group grid = cg::this_grid();
    const int b   = blockIdx.x;
    const int tid = threadIdx.x;

    // ================= phase 0: W transpose + bf16 convert =================
    if (b < 64) {
        const int kt = b & 7;          // k-tile
        const int nt = b >> 3;         // n-tile
        {
            int kl = tid >> 3, n4 = (tid & 7) * 4;
            float4 v = *(const float4*)(W + (size_t)(kt * 32 + kl) * FOUT + nt * 32 + n4);
            sm.ls[kl][n4 + 0] = v.x; sm.ls[kl][n4 + 1] = v.y;
            sm.ls[kl][n4 + 2] = v.z; sm.ls[kl][n4 + 3] = v.w;
        }
        __syncthreads();
        {
            int nl = tid >> 3, k4 = (tid & 7) * 4;
            ushort4 o;
            o.x = f2bf(sm.ls[k4 + 0][nl]);
            o.y = f2bf(sm.ls[k4 + 1][nl]);
            o.z = f2bf(sm.ls[k4 + 2][nl]);
            o.w = f2bf(sm.ls[k4 + 3][nl]);
            *(ushort4*)(Wt + (size_t)(nt * 32 + nl) * FIN + kt * 32 + k4) = o;
        }
    }
    __threadfence();               // Wt -> visible cross-XCD
    grid.sync();

    // ================= phase 1: gemm (M=64 x N=128 tiles) ==================
    {
        const int lane = tid & 63;
        const int wv   = tid >> 6;
        const int l16  = lane & 15;
        const int q    = lane >> 4;

        for (int t = b; t < GTILES; t += NBLK) {
            // swizzle: pairs of tiles 8 apart share rows -> same XCD (%512 keeps %8)
            int rb, cb;
            if (t < 768) { rb = ((t >> 4) << 3) + (t & 7); cb = (t >> 3) & 1; }
            else         { const int t2 = t - 768; rb = 384 + (t2 >> 1); cb = t2 & 1; }
            const int row0 = rb * 64;
            const int n0   = cb * 128 + wv * 32;

            __syncthreads();       // protect As from previous tile's readers
            {   // stage full K: thread -> row (tid>>2), 64 k at (tid&3)*64
                const int r     = tid >> 2;
                const int kbase = (tid & 3) * 64;
                int gr = row0 + r;
                if (gr >= N_NODES) gr = N_NODES - 1;   // clamped rows never stored
                const float* p = x + (size_t)gr * FIN + kbase;
                float4 v[16];
                #pragma unroll
                for (int i = 0; i < 16; ++i) v[i] = *(const float4*)(p + i * 4);
                #pragma unroll
                for (int i = 0; i < 8; ++i) {
                    uint4 pk;
                    pk.x = pack2(v[2*i].x,   v[2*i].y);
                    pk.y = pack2(v[2*i].z,   v[2*i].w);
                    pk.z = pack2(v[2*i+1].x, v[2*i+1].y);
                    pk.w = pack2(v[2*i+1].z, v[2*i+1].w);
                    *(uint4*)&sm.As[r][kbase + i * 8] = pk;
                }
            }
            __syncthreads();

            f32x4 acc[4][2];
            #pragma unroll
            for (int i = 0; i < 4; ++i)
                #pragma unroll
                for (int j = 0; j < 2; ++j) acc[i][j] = (f32x4)0.f;

            const ushort* wp0 = Wt + (size_t)(n0 + l16) * FIN;
            const ushort* wp1 = wp0 + (size_t)16 * FIN;

            #pragma unroll
            for (int kk = 0; kk < FIN; kk += 32) {
                const int k0 = kk + q * 8;
                s16x8 a[4], bfr[2];
                bfr[0] = *(const s16x8*)(wp0 + k0);
                bfr[1] = *(const s16x8*)(wp1 + k0);
                #pragma unroll
                for (int mt = 0; mt < 4; ++mt)
                    a[mt] = *(const s16x8*)&sm.As[mt * 16 + l16][k0];
                #pragma unroll
                for (int mt = 0; mt < 4; ++mt)
                    #pragma unroll
                    for (int ct = 0; ct < 2; ++ct)
                        acc[mt][ct] = __builtin_amdgcn_mfma_f32_16x16x32_bf16(a[mt], bfr[ct], acc[mt][ct], 0, 0, 0);
            }

            // epilogue: +bias, relu, bf16 store.  D: col=lane&15, row=q*4+reg
            #pragma unroll
            for (int ct = 0; ct < 2; ++ct) {
                const int col = n0 + ct * 16 + l16;
                const float bv = bias[col];
                #pragma unroll
                for (int mt = 0; mt < 4; ++mt) {
                    #pragma unroll
                    for (int rr = 0; rr < 4; ++rr) {
                        int row = row0 + mt * 16 + q * 4 + rr;
                        if (row < N_NODES)
                            y[(size_t)row * FOUT + col] = f2bf(fmaxf(acc[mt][ct][rr] + bv, 0.f));
                    }
                }
            }
        }
    }
    __threadfence();               // y -> visible cross-XCD (buffer_wbl2)
    grid.sync();

    // ================= phase 2: gather max-pool ============================
    {
        const int lane   = tid & 63;
        const int g      = lane >> 3;     // node-group within wave (0..7)
        const int gl     = lane & 7;      // lane within group
        const int wv     = tid >> 6;
        const int node_l = wv * 8 + g;

        for (int u = b; u < PUNITS; u += NBLK) {
            const int chunk = u & 3;      // == b&3 (512≡0 mod 4): XCD-pinned slice
            const int nb    = u >> 2;

            __syncthreads();              // protect nidx from previous readers
            {   // stage 32 nodes x 32 indices (coalesced 4KB)
                const int nl = tid >> 3, k4 = (tid & 7) * 4;
                int gn = nb * 32 + nl;
                if (gn >= N_NODES) gn = N_NODES - 1;
                *(int4*)&sm.nidx[nl][k4] = *(const int4*)(neigh + (size_t)gn * KFAN + k4);
            }
            __syncthreads();

            const int n = nb * 32 + node_l;
            const ushort* yc = y + chunk * 64 + gl * 8;

            s16x8 acc0 = (s16x8)0, acc1 = (s16x8)0;
            #pragma unroll
            for (int k = 0; k < KFAN; k += 4) {
                const int4 ii = *(const int4*)&sm.nidx[node_l][k];
                s16x8 c0 = *(const s16x8*)(yc + (size_t)ii.x * FOUT);
                s16x8 c1 = *(const s16x8*)(yc + (size_t)ii.y * FOUT);
                s16x8 c2 = *(const s16x8*)(yc + (size_t)ii.z * FOUT);
                s16x8 c3 = *(const s16x8*)(yc + (size_t)ii.w * FOUT);
                acc0 = __builtin_elementwise_max(acc0, c0);
                acc1 = __builtin_elementwise_max(acc1, c1);
                acc0 = __builtin_elementwise_max(acc0, c2);
                acc1 = __builtin_elementwise_max(acc1, c3);
            }
            acc0 = __builtin_elementwise_max(acc0, acc1);

            if (n < N_NODES) {
                f32x4 o0, o1;
                o0.x = __uint_as_float(((unsigned int)(ushort)acc0[0]) << 16);
                o0.y = __uint_as_float(((unsigned int)(ushort)acc0[1]) << 16);
                o0.z = __uint_as_float(((unsigned int)(ushort)acc0[2]) << 16);
                o0.w = __uint_as_float(((unsigned int)(ushort)acc0[3]) << 16);
                o1.x = __uint_as_float(((unsigned int)(ushort)acc0[4]) << 16);
                o1.y = __uint_as_float(((unsigned int)(ushort)acc0[5]) << 16);
                o1.z = __uint_as_float(((unsigned int)(ushort)acc0[6]) << 16);
                o1.w = __uint_as_float(((unsigned int)(ushort)acc0[7]) << 16);
                float* op = out + (size_t)n * FOUT + chunk * 64 + gl * 8;
                __builtin_nontemporal_store(o0, (f32x4*)op);
                __builtin_nontemporal_store(o1, (f32x4*)(op + 4));
            }
        }
    }
}

extern "C" void kernel_launch(void* const* d_in, const int* in_sizes, int n_in,
                              void* d_out, int out_size, void* d_ws, size_t ws_size,
                              hipStream_t stream) {
    const float* x     = (const float*)d_in[0];
    const int*   neigh = (const int*)  d_in[1];
    const float* W     = (const float*)d_in[2];
    const float* bias  = (const float*)d_in[3];
    float*       out   = (float*)d_out;
    ushort*      y     = (ushort*)d_ws;                         // 12.8 MB
    ushort*      Wt    = (ushort*)((char*)d_ws + (32u << 20));  // 128 KB @ +32MB

    void* args[] = {(void*)&x, (void*)&neigh, (void*)&W, (void*)&bias,
                    (void*)&out, (void*)&y, (void*)&Wt};
    hipLaunchCooperativeKernel((void*)fused, dim3(NBLK), dim3(256),
                               args, 0, stream);
}

// Round 3
// 122.311 us; speedup vs baseline: 2.7901x; 2.7901x over previous
//
#include <hip/hip_runtime.h>
#include <hip/hip_bf16.h>

#define N_NODES 25000
#define KFAN    32
#define FIN     256
#define FOUT    256

typedef float  f32x4  __attribute__((ext_vector_type(4)));
typedef short  s16x8  __attribute__((ext_vector_type(8)));

// round-to-nearest-even fp32 -> bf16 bits
__device__ __forceinline__ ushort f2bf(float f) {
    unsigned int u = __float_as_uint(f);
    u += 0x7fffu + ((u >> 16) & 1u);
    return (ushort)(u >> 16);
}

// packed RNE conversion: lo = bf16(a), hi = bf16(b) in one instruction
__device__ __forceinline__ unsigned int pack2(float a, float b) {
    unsigned int r;
    asm("v_cvt_pk_bf16_f32 %0, %1, %2" : "=v"(r) : "v"(a), "v"(b));
    return r;
}

// ---------------- Kernel 0: Wt[n][k] = bf16(W[k][n])  (256x256) ------------
__global__ __launch_bounds__(256) void transpose_w(
    const float* __restrict__ W, ushort* __restrict__ Wt)
{
    __shared__ float ls[32][33];
    const int bid = blockIdx.x;        // 64 blocks
    const int kt  = bid & 7;           // k-tile
    const int nt  = bid >> 3;          // n-tile
    const int t   = threadIdx.x;

    {
        int kl = t >> 3, n4 = (t & 7) * 4;
        float4 v = *(const float4*)(W + (size_t)(kt * 32 + kl) * FOUT + nt * 32 + n4);
        ls[kl][n4 + 0] = v.x; ls[kl][n4 + 1] = v.y;
        ls[kl][n4 + 2] = v.z; ls[kl][n4 + 3] = v.w;
    }
    __syncthreads();
    {
        int nl = t >> 3, k4 = (t & 7) * 4;
        ushort4 o;
        o.x = f2bf(ls[k4 + 0][nl]);
        o.y = f2bf(ls[k4 + 1][nl]);
        o.z = f2bf(ls[k4 + 2][nl]);
        o.w = f2bf(ls[k4 + 3][nl]);
        *(ushort4*)(Wt + (size_t)(nt * 32 + nl) * FIN + kt * 32 + k4) = o;
    }
}

// ---------------- Kernel 1: y = relu(x @ W + b) via MFMA bf16 --------------
// Full-width tiles: M=32 x N=256 -> x is read from HBM exactly ONCE (was 2
// col-half passes).  Block 256 thr (4 waves); wave wv owns 64 cols
// (2 row-tiles x 4 col-tiles of 16x16, mfma_f32_16x16x32_bf16).
// Full-K LDS staging (2 barriers/block).  Staging map row=t>>3, c=t&7,
// 16-float groups at stride 128: LDS write quad = (row+2c+s)&7 -> 2-way
// (free), vs 4-way in the previous map (3.0M conflict cycles measured).
__global__ __launch_bounds__(256) void gemm_mfma(
    const float*  __restrict__ x,     // [N][FIN] fp32
    const ushort* __restrict__ Wt,    // [FOUT][FIN] bf16 bits (W^T)
    const float*  __restrict__ bias,  // [FOUT]
    ushort*       __restrict__ y)     // [N][FOUT] bf16 bits
{
    __shared__ ushort As[32][264];    // 16.9 KB; row 528B = 132 dw (33 quads, odd)

    const int tid  = threadIdx.x;
    const int lane = tid & 63;
    const int wv   = tid >> 6;
    const int l16  = lane & 15;
    const int q    = lane >> 4;       // quad 0..3
    const int row0 = blockIdx.x * 32;
    const int n0   = wv * 64;

    // ---- stage full K: thread t -> row t>>3, float cols c*16+{0..15} and
    //      c*16+128+{0..15}  (c = t&7) ----
    {
        const int r = tid >> 3;
        const int c = tid & 7;
        int gr = row0 + r;
        if (gr >= N_NODES) gr = N_NODES - 1;   // clamped rows never stored
        const float* p = x + (size_t)gr * FIN + c * 16;
        #pragma unroll
        for (int i = 0; i < 2; ++i) {
            float4 v0 = *(const float4*)(p + i * 128);
            float4 v1 = *(const float4*)(p + i * 128 + 4);
            float4 v2 = *(const float4*)(p + i * 128 + 8);
            float4 v3 = *(const float4*)(p + i * 128 + 12);
            uint4 pa, pb;
            pa.x = pack2(v0.x, v0.y); pa.y = pack2(v0.z, v0.w);
            pa.z = pack2(v1.x, v1.y); pa.w = pack2(v1.z, v1.w);
            pb.x = pack2(v2.x, v2.y); pb.y = pack2(v2.z, v2.w);
            pb.z = pack2(v3.x, v3.y); pb.w = pack2(v3.z, v3.w);
            *(uint4*)&As[r][i * 128 + c * 16]     = pa;
            *(uint4*)&As[r][i * 128 + c * 16 + 8] = pb;
        }
    }
    __syncthreads();

    f32x4 acc[2][4];
    #pragma unroll
    for (int i = 0; i < 2; ++i)
        #pragma unroll
        for (int j = 0; j < 4; ++j) acc[i][j] = (f32x4)0.f;

    const ushort* wp[4];
    #pragma unroll
    for (int ct = 0; ct < 4; ++ct)
        wp[ct] = Wt + (size_t)(n0 + ct * 16 + l16) * FIN;

    #pragma unroll
    for (int kk = 0; kk < FIN; kk += 32) {
        const int k0 = kk + q * 8;
        s16x8 a[2], bfr[4];
        #pragma unroll
        for (int ct = 0; ct < 4; ++ct)
            bfr[ct] = *(const s16x8*)(wp[ct] + k0);
        #pragma unroll
        for (int mt = 0; mt < 2; ++mt)
            a[mt] = *(const s16x8*)&As[mt * 16 + l16][k0];
        #pragma unroll
        for (int mt = 0; mt < 2; ++mt)
            #pragma unroll
            for (int ct = 0; ct < 4; ++ct)
                acc[mt][ct] = __builtin_amdgcn_mfma_f32_16x16x32_bf16(a[mt], bfr[ct], acc[mt][ct], 0, 0, 0);
    }

    // epilogue: +bias, relu, bf16 store.  D layout: col=lane&15, row=q*4+reg
    // (scalar 2B stores measured exactly-compulsory WRITE_SIZE in round 2)
    #pragma unroll
    for (int ct = 0; ct < 4; ++ct) {
        const int col = n0 + ct * 16 + l16;
        const float bv = bias[col];
        #pragma unroll
        for (int mt = 0; mt < 2; ++mt) {
            #pragma unroll
            for (int rr = 0; rr < 4; ++rr) {
                int row = row0 + mt * 16 + q * 4 + rr;
                if (row < N_NODES)
                    y[(size_t)row * FOUT + col] = f2bf(fmaxf(acc[mt][ct][rr] + bv, 0.f));
            }
        }
    }
}

// ---------------- Kernel 2: out[n][o] = max_k y[neigh[n][k]][o] ------------
// 64-col chunks pinned per-XCD (y slice 3.2MB < 4MB L2), 16B gather loads:
// 8 lanes per node-group, 8 nodes per wave, 32 nodes per block.
// Index distribution via 4.6KB LDS tile + ds_read_b128 (same-address
// broadcast within each 8-lane group).  Packed i16-max on bf16 bits
// (valid: relu => y >= 0); dual accumulators halve the dep chain.
__global__ __launch_bounds__(256) void pool_max(
    const ushort* __restrict__ y,     // [N][FOUT] bf16 bits
    const int*    __restrict__ neigh, // [N][KFAN]
    float*        __restrict__ out)   // [N][FOUT] fp32
{
    __shared__ int nidx[32][36];

    const int bid   = blockIdx.x;
    const int chunk = bid & 3;        // 64-col chunk, XCD-affine under %8 RR
    const int nb    = bid >> 2;
    const int tid   = threadIdx.x;

    {   // stage 32 nodes x 32 indices (coalesced 4KB)
        const int nl = tid >> 3, k4 = (tid & 7) * 4;
        int gn = nb * 32 + nl;
        if (gn >= N_NODES) gn = N_NODES - 1;
        *(int4*)&nidx[nl][k4] = *(const int4*)(neigh + (size_t)gn * KFAN + k4);
    }
    __syncthreads();

    const int lane   = tid & 63;
    const int g      = lane >> 3;     // node-group within wave (0..7)
    const int gl     = lane & 7;      // lane within group
    const int wv     = tid >> 6;
    const int node_l = wv * 8 + g;
    const int n      = nb * 32 + node_l;

    const ushort* yc = y + chunk * 64 + gl * 8;

    s16x8 acc0 = (s16x8)0, acc1 = (s16x8)0;
    #pragma unroll
    for (int k = 0; k < KFAN; k += 4) {
        const int4 ii = *(const int4*)&nidx[node_l][k];
        s16x8 c0 = *(const s16x8*)(yc + (size_t)ii.x * FOUT);
        s16x8 c1 = *(const s16x8*)(yc + (size_t)ii.y * FOUT);
        s16x8 c2 = *(const s16x8*)(yc + (size_t)ii.z * FOUT);
        s16x8 c3 = *(const s16x8*)(yc + (size_t)ii.w * FOUT);
        acc0 = __builtin_elementwise_max(acc0, c0);
        acc1 = __builtin_elementwise_max(acc1, c1);
        acc0 = __builtin_elementwise_max(acc0, c2);
        acc1 = __builtin_elementwise_max(acc1, c3);
    }
    acc0 = __builtin_elementwise_max(acc0, acc1);

    if (n < N_NODES) {
        f32x4 o0, o1;
        o0.x = __uint_as_float(((unsigned int)(ushort)acc0[0]) << 16);
        o0.y = __uint_as_float(((unsigned int)(ushort)acc0[1]) << 16);
        o0.z = __uint_as_float(((unsigned int)(ushort)acc0[2]) << 16);
        o0.w = __uint_as_float(((unsigned int)(ushort)acc0[3]) << 16);
        o1.x = __uint_as_float(((unsigned int)(ushort)acc0[4]) << 16);
        o1.y = __uint_as_float(((unsigned int)(ushort)acc0[5]) << 16);
        o1.z = __uint_as_float(((unsigned int)(ushort)acc0[6]) << 16);
        o1.w = __uint_as_float(((unsigned int)(ushort)acc0[7]) << 16);
        float* op = out + (size_t)n * FOUT + chunk * 64 + gl * 8;
        __builtin_nontemporal_store(o0, (f32x4*)op);
        __builtin_nontemporal_store(o1, (f32x4*)(op + 4));
    }
}

extern "C" void kernel_launch(void* const* d_in, const int* in_sizes, int n_in,
                              void* d_out, int out_size, void* d_ws, size_t ws_size,
                              hipStream_t stream) {
    const float* x     = (const float*)d_in[0];
    const int*   neigh = (const int*)  d_in[1];
    const float* W     = (const float*)d_in[2];
    const float* bias  = (const float*)d_in[3];
    float*       out   = (float*)d_out;
    ushort*      y     = (ushort*)d_ws;                         // 12.8 MB
    ushort*      Wt    = (ushort*)((char*)d_ws + (32u << 20));  // 128 KB @ +32MB

    transpose_w<<<64, 256, 0, stream>>>(W, Wt);

    const int gblocks = (N_NODES + 31) / 32;                    // 782
    gemm_mfma<<<gblocks, 256, 0, stream>>>(x, Wt, bias, y);

    const int nblocks = ((N_NODES + 31) / 32) * 4;              // 3128
    pool_max<<<nblocks, 256, 0, stream>>>(y, neigh, out);
}